// Round 13
// baseline (157.310 us; speedup 1.0000x reference)
//
#include <hip/hip_runtime.h>
#include <stdint.h>
#include <stddef.h>

typedef __attribute__((ext_vector_type(8))) short short8;
typedef __attribute__((ext_vector_type(4))) float f32x4;
typedef __attribute__((ext_vector_type(4))) short short4v;

__device__ __forceinline__ short f2bf(float f) {
  unsigned u = __builtin_bit_cast(unsigned, f);
  u = (u + 0x7fffu + ((u >> 16) & 1u)) >> 16;
  return (short)u;
}

__device__ __forceinline__ float bf2f(short s) {
  unsigned u = ((unsigned)(unsigned short)s) << 16;
  return __builtin_bit_cast(float, u);
}

__device__ __forceinline__ void gload16(const void* g, void* l) {
  __builtin_amdgcn_global_load_lds(
      (const __attribute__((address_space(1))) unsigned int*)g,
      (__attribute__((address_space(3))) unsigned int*)l, 16, 0, 0);
}

// ---------------- conversion kernels ----------------

__global__ __launch_bounds__(256)
void cvt_misc_k(const float* __restrict__ x, const float* __restrict__ nw1,
                const float* __restrict__ lb2, short* __restrict__ xb,
                short* __restrict__ BTn, short* __restrict__ BT2) {
  const int bx = blockIdx.x;
  if (bx < 3072) {
    const int i = bx * 256 + threadIdx.x;
    const float4 v = ((const float4*)x)[i];
    short4v o;
    o.x = f2bf(v.x); o.y = f2bf(v.y); o.z = f2bf(v.z); o.w = f2bf(v.w);
    *(short4v*)(xb + (size_t)i * 4) = o;
  } else if (bx < 6144) {
    const int idx = (bx - 3072) * 256 + threadIdx.x;  // 1024*768
    const int i = idx % 768;
    const int nh = idx / 768;
    float v = 0.f;
    if (nh < 1008) v = nw1[((size_t)(nh >> 4) * 768 + i) * 16 + (nh & 15)];
    BTn[idx] = f2bf(v);
  } else {
    const int idx = (bx - 6144) * 256 + threadIdx.x;  // 768*64
    const int o = idx >> 6, l = idx & 63;
    BT2[(size_t)o * 8256 + 8192 + l] = f2bf(lb2[(size_t)l * 768 + o]);
  }
}

// Fused: blocks [0,512) = node GEMM hn = xb @ BTn^T (4096x1024, K=768, BM=64);
// blocks [512, 3584) = weight transposes (lw1->BT1, lw2->BT2).
__global__ __launch_bounds__(256, 4)
void node_cvt_k(const short* __restrict__ xb, const short* __restrict__ BTn,
                float* __restrict__ hn, const float* __restrict__ lw1,
                const float* __restrict__ lw2, short* __restrict__ BT1,
                short* __restrict__ BT2) {
  __shared__ char sh[24576];
  const int tid = threadIdx.x;
  if (blockIdx.x < 512) {
    constexpr int ABYTES = 64 * 128;
    const int lane = tid & 63, wid = tid >> 6;
    const int wm = wid >> 1, wn = wid & 1;
    const int sid = (blockIdx.x & 7) * 64 + (blockIdx.x >> 3);
    const int xg = sid % 8, yg = sid / 8;
    const int m0 = yg * 64, n0 = xg * 128;
    f32x4 acc[2][4];
    const f32x4 zero = {0.f, 0.f, 0.f, 0.f};
#pragma unroll
    for (int i = 0; i < 2; ++i)
#pragma unroll
      for (int j = 0; j < 4; ++j) acc[i][j] = zero;
    for (int ki = 0; ki < 12; ++ki) {
      const int k0 = ki * 64;
      __syncthreads();
#pragma unroll
      for (int s = 0; s < 6; ++s) {
        const int off = s * 4096 + tid * 16;
        const short* src;
        if (off < ABYTES) {
          const int r = off >> 7;
          const int cs = ((off >> 4) & 7) ^ (r & 7);
          src = xb + (size_t)(m0 + r) * 768 + k0 + cs * 8;
        } else {
          const int o2 = off - ABYTES;
          const int r = o2 >> 7;
          const int cs = ((o2 >> 4) & 7) ^ (r & 7);
          src = BTn + (size_t)(n0 + r) * 768 + k0 + cs * 8;
        }
        gload16(src, sh + off);
      }
      __syncthreads();
#pragma unroll
      for (int kk = 0; kk < 2; ++kk) {
        const int chunk = kk * 4 + (lane >> 4);
        short8 af[2], bfr[4];
#pragma unroll
        for (int i = 0; i < 2; ++i) {
          const int row = wm * 32 + i * 16 + (lane & 15);
          af[i] = *(const short8*)(sh + row * 128 + ((chunk ^ (row & 7)) << 4));
        }
#pragma unroll
        for (int j = 0; j < 4; ++j) {
          const int row = wn * 64 + j * 16 + (lane & 15);
          bfr[j] = *(const short8*)(sh + ABYTES + row * 128 + ((chunk ^ (row & 7)) << 4));
        }
#pragma unroll
        for (int i = 0; i < 2; ++i)
#pragma unroll
          for (int j = 0; j < 4; ++j)
            acc[i][j] = __builtin_amdgcn_mfma_f32_16x16x32_bf16(af[i], bfr[j], acc[i][j], 0, 0, 0);
      }
    }
    const int row_base = m0 + wm * 32 + (lane >> 4) * 4;
    const int col_base = n0 + wn * 64 + (lane & 15);
#pragma unroll
    for (int i = 0; i < 2; ++i)
#pragma unroll
      for (int j = 0; j < 4; ++j)
#pragma unroll
        for (int r = 0; r < 4; ++r)
          hn[(size_t)(row_base + i * 16 + r) * 1024 + col_base + j * 16] = acc[i][j][r];
  } else {
    float (*tile)[65] = (float(*)[65])sh;
    const int cb = blockIdx.x - 512;  // [0,3072)
    const int z = cb / 24, rem = cb % 24;
    const int by = rem / 12, bxx = rem % 12;
    const int h0 = by * 64, i0 = bxx * 64;
    if (z < 64) {
      const int l = z;
#pragma unroll
      for (int t = 0; t < 16; ++t) {
        const int e = t * 256 + tid;
        const int ii = e >> 6, hh = e & 63;
        tile[ii][hh] = lw1[(size_t)l * 98304 + (size_t)(i0 + ii) * 128 + (h0 + hh)];
      }
      __syncthreads();
#pragma unroll
      for (int t = 0; t < 16; ++t) {
        const int e = t * 256 + tid;
        const int hh = e >> 6, ii = e & 63;
        BT1[(size_t)(l * 128 + h0 + hh) * 768 + i0 + ii] = f2bf(tile[ii][hh]);
      }
    } else {
      const int l = z - 64;
      const int o0 = i0;
#pragma unroll
      for (int t = 0; t < 16; ++t) {
        const int e = t * 256 + tid;
        const int hh = e >> 6, oo = e & 63;
        tile[hh][oo] = lw2[(size_t)l * 98304 + (size_t)(h0 + hh) * 768 + (o0 + oo)];
      }
      __syncthreads();
#pragma unroll
      for (int t = 0; t < 16; ++t) {
        const int e = t * 256 + tid;
        const int oo = e >> 6, hh = e & 63;
        BT2[(size_t)(o0 + oo) * 8256 + l * 128 + h0 + hh] = f2bf(tile[hh][oo]);
      }
    }
  }
}

// ---------------- gate kernel (vectorized loads) ----------------
__global__ __launch_bounds__(256)
void gates_k(const float* __restrict__ hn, const float* __restrict__ nb1,
             const float* __restrict__ nw2, const float* __restrict__ nb2,
             float* __restrict__ wgt, short* __restrict__ hs) {
  const int b = blockIdx.x * 4 + (threadIdx.x >> 6);
  const int lane = threadIdx.x & 63;
  float c = 0.f;
  if (lane < 63) {
    float s = nb2[lane];
    const float4* h4 = (const float4*)(hn + (size_t)b * 1024 + lane * 16);
    const float4* b4 = (const float4*)(nb1 + lane * 16);
    const float4* w4 = (const float4*)(nw2 + lane * 16);
#pragma unroll
    for (int j = 0; j < 4; ++j) {
      const float4 hv = h4[j], bv = b4[j], wv = w4[j];
      s += fmaxf(hv.x + bv.x, 0.f) * wv.x;
      s += fmaxf(hv.y + bv.y, 0.f) * wv.y;
      s += fmaxf(hv.z + bv.z, 0.f) * wv.z;
      s += fmaxf(hv.w + bv.w, 0.f) * wv.w;
    }
    c = 1.f / (1.f + expf(-s));
  }
  float w = 1.f;
#pragma unroll
  for (int lvl = 0; lvl < 6; ++lvl) {
    const int idx = (1 << lvl) - 1 + (lane >> (6 - lvl));
    const float g = __shfl(c, idx, 64);
    w *= ((lane >> (5 - lvl)) & 1) ? (1.f - g) : g;
  }
  wgt[(size_t)b * 64 + lane] = w;
  hs[(size_t)b * 8256 + 8192 + lane] = f2bf(w);
}

// ---------------- gemm8x: 256x256 8-phase GEMM ----------------
// Identical to the R10/R12-proven config EXCEPT: the counted vmcnt gate moved
// from before the phase's MFMA to after it (still before the closing barrier,
// which is what releases the next phase's ds_reads of the staged buffer).
// This donates the ~470cyc MFMA block as extra HBM-latency cover at the gate.
// EPI1 (GEMM1): grid 512 = 32xg x 16yg, 2D XCD chunk (8x8 per XCD), KT=12.
// EPI0 (GEMM2): grid 240 = 3xg x 16yg x 5z (splits 26,26,26,26,25; z=4 odd tail).
//   z0->out f32, z1/z2->P f32, z3/z4->Q bf16.
template <int EPI>
__global__ __launch_bounds__(512, 2)
void gemm8x(const short* __restrict__ A, const short* __restrict__ B,
            void* __restrict__ C0, float* __restrict__ P1, float* __restrict__ P2,
            short* __restrict__ Q1, short* __restrict__ Q2,
            const float* __restrict__ bias, const float* __restrict__ wgt) {
  constexpr int LDA = EPI ? 768 : 8256;
  constexpr int LDB = EPI ? 768 : 8256;
  constexpr int LDC = EPI ? 8256 : 768;
  constexpr int ABYTES = 256 * 128;
  constexpr int TILEB = 2 * ABYTES;
  __shared__ char lds[2 * TILEB];

  const int tid = threadIdx.x, lane = tid & 63, wid = tid >> 6;
  const int wm = wid >> 2, wn = wid & 3;

  const int c = blockIdx.x & 7, ii = blockIdx.x >> 3;
  int xg, yg, kt0, GKT, zz;
  if constexpr (EPI == 1) {
    xg = ((c & 3) << 3) + (ii & 7);   // [0,32)
    yg = ((c >> 2) << 3) + (ii >> 3); // [0,16)
    kt0 = 0; GKT = 12; zz = 0;
  } else {
    const int uid = c * 30 + ii;  // [0,240)
    zz = uid / 48;                // [0,5)
    const int r = uid % 48;
    xg = r % 3; yg = r / 3;
    kt0 = zz * 26;
    GKT = (zz == 4) ? 25 : 26;
  }
  const int m0 = yg * 256, n0 = xg * 256;

  f32x4 acc[8][4];
  const f32x4 zero = {0.f, 0.f, 0.f, 0.f};
#pragma unroll
  for (int i = 0; i < 8; ++i)
#pragma unroll
    for (int j = 0; j < 4; ++j) acc[i][j] = zero;

  auto STG = [&](int buf, int mat, int h, int gk) {
    const int k0 = (kt0 + gk) * 64;
    char* dst = lds + buf * TILEB + mat * ABYTES + h * 16384;
    const short* base = mat ? B : A;
    const int ld = mat ? LDB : LDA;
    const int r0 = (mat ? n0 : m0) + h * 128;
#pragma unroll
    for (int s = 0; s < 2; ++s) {
      const int off = s * 8192 + tid * 16;
      const int r = off >> 7;
      const int cs = ((off >> 4) & 7) ^ (r & 7);
      gload16(base + (size_t)(r0 + r) * ld + k0 + cs * 8, dst + off);
    }
  };

  short8 bfrag[4][2];
  auto RD_B = [&](int buf) {
    const char* bB = lds + buf * TILEB + ABYTES;
#pragma unroll
    for (int j = 0; j < 4; ++j)
#pragma unroll
      for (int kk = 0; kk < 2; ++kk) {
        const int row = wn * 64 + j * 16 + (lane & 15);
        const int chunk = kk * 4 + (lane >> 4);
        bfrag[j][kk] = *(const short8*)(bB + row * 128 + ((chunk ^ (row & 7)) << 4));
      }
  };

  // phase: [rdB?]; ds_read A-quad; stage issues; barrier; MFMA; [vmcnt]; barrier
  auto PH = [&](int buf, int q, bool rdB, int vm, auto&& stages) {
    if (rdB) RD_B(buf);
    const char* bA = lds + buf * TILEB;
    short8 af[2][2];
#pragma unroll
    for (int i = 0; i < 2; ++i)
#pragma unroll
      for (int kk = 0; kk < 2; ++kk) {
        const int row = wm * 128 + q * 32 + i * 16 + (lane & 15);
        const int chunk = kk * 4 + (lane >> 4);
        af[i][kk] = *(const short8*)(bA + row * 128 + ((chunk ^ (row & 7)) << 4));
      }
    stages();
    __builtin_amdgcn_s_barrier();
    __builtin_amdgcn_s_setprio(1);
#pragma unroll
    for (int kk = 0; kk < 2; ++kk)
#pragma unroll
      for (int i = 0; i < 2; ++i)
#pragma unroll
        for (int j = 0; j < 4; ++j)
          acc[q * 2 + i][j] =
              __builtin_amdgcn_mfma_f32_16x16x32_bf16(af[i][kk], bfrag[j][kk], acc[q * 2 + i][j], 0, 0, 0);
    __builtin_amdgcn_s_setprio(0);
    if (vm == 4) asm volatile("s_waitcnt vmcnt(4)" ::: "memory");
    else if (vm == 0) asm volatile("s_waitcnt vmcnt(0)" ::: "memory");
    __builtin_amdgcn_s_barrier();
  };

  // prologue: tile 0 (8 loads) + B(1) (4 loads); wait tile0 (must block before reads)
  STG(0, 0, 0, 0); STG(0, 0, 1, 0); STG(0, 1, 0, 0); STG(0, 1, 1, 0);
  STG(1, 1, 0, 1); STG(1, 1, 1, 1);
  asm volatile("s_waitcnt vmcnt(4)" ::: "memory");
  __builtin_amdgcn_s_barrier();

  const int iters = GKT >> 1;
  for (int it = 0; it < iters; ++it) {
    const int t0 = it * 2;
    const bool s2 = t0 + 2 < GKT, s3 = t0 + 3 < GKT;
    PH(0, 0, true, -1, [&] { STG(1, 0, 0, t0 + 1); });
    PH(0, 1, false, -1, [&] {
      STG(1, 0, 1, t0 + 1);
      if (s2) STG(0, 1, 0, t0 + 2);
    });
    PH(0, 2, false, -1, [&] { if (s2) STG(0, 1, 1, t0 + 2); });
    PH(0, 3, false, s2 ? 4 : 0, [] {});
    PH(1, 0, true, -1, [&] { if (s2) STG(0, 0, 0, t0 + 2); });
    PH(1, 1, false, -1, [&] { if (s2) STG(0, 0, 1, t0 + 2); });
    PH(1, 2, false, -1, [&] { if (s3) STG(1, 1, 0, t0 + 3); });
    PH(1, 3, false, s2 ? 4 : -1, [&] { if (s3) STG(1, 1, 1, t0 + 3); });
  }
  if (GKT & 1) {  // odd tail (EPI0 z=4): tile GKT-1 fully staged in buf0
    asm volatile("s_waitcnt vmcnt(0)" ::: "memory");
    __builtin_amdgcn_s_barrier();
    RD_B(0);
    const char* bA = lds;
#pragma unroll
    for (int q = 0; q < 4; ++q) {
      short8 af[2][2];
#pragma unroll
      for (int i = 0; i < 2; ++i)
#pragma unroll
        for (int kk = 0; kk < 2; ++kk) {
          const int row = wm * 128 + q * 32 + i * 16 + (lane & 15);
          const int chunk = kk * 4 + (lane >> 4);
          af[i][kk] = *(const short8*)(bA + row * 128 + ((chunk ^ (row & 7)) << 4));
        }
      __builtin_amdgcn_s_setprio(1);
#pragma unroll
      for (int kk = 0; kk < 2; ++kk)
#pragma unroll
        for (int i = 0; i < 2; ++i)
#pragma unroll
          for (int j = 0; j < 4; ++j)
            acc[q * 2 + i][j] =
                __builtin_amdgcn_mfma_f32_16x16x32_bf16(af[i][kk], bfrag[j][kk], acc[q * 2 + i][j], 0, 0, 0);
      __builtin_amdgcn_s_setprio(0);
    }
  }

  if constexpr (EPI == 1) {
    short* C = (short*)C0;
#pragma unroll
    for (int mi = 0; mi < 8; ++mi) {
      const int row_base = m0 + wm * 128 + mi * 16 + (lane >> 4) * 4;
#pragma unroll
      for (int j = 0; j < 4; ++j) {
        const int col = n0 + wn * 64 + j * 16 + (lane & 15);
        const int leaf = col >> 7;
        const float b = bias[col];
#pragma unroll
        for (int r = 0; r < 4; ++r) {
          const int row = row_base + r;
          const float v = fmaxf(acc[mi][j][r] + b, 0.f) * wgt[(size_t)row * 64 + leaf];
          C[(size_t)row * LDC + col] = f2bf(v);
        }
      }
    }
  } else {
    if (zz <= 2) {
      float* C = (zz == 0) ? (float*)C0 : (zz == 1 ? P1 : P2);
#pragma unroll
      for (int mi = 0; mi < 8; ++mi) {
        const int row_base = m0 + wm * 128 + mi * 16 + (lane >> 4) * 4;
#pragma unroll
        for (int j = 0; j < 4; ++j) {
          const int col = n0 + wn * 64 + j * 16 + (lane & 15);
#pragma unroll
          for (int r = 0; r < 4; ++r)
            C[(size_t)(row_base + r) * LDC + col] = acc[mi][j][r];
        }
      }
    } else {
      short* Q = (zz == 3) ? Q1 : Q2;
#pragma unroll
      for (int mi = 0; mi < 8; ++mi) {
        const int row_base = m0 + wm * 128 + mi * 16 + (lane >> 4) * 4;
#pragma unroll
        for (int j = 0; j < 4; ++j) {
          const int col = n0 + wn * 64 + j * 16 + (lane & 15);
#pragma unroll
          for (int r = 0; r < 4; ++r)
            Q[(size_t)(row_base + r) * LDC + col] = f2bf(acc[mi][j][r]);
        }
      }
    }
  }
}

// ---------------- split-K reduce: out += p1 + p2 + q1 + q2 ----------------
__global__ __launch_bounds__(256)
void reduce_k(float* __restrict__ out, const float* __restrict__ p1,
              const float* __restrict__ p2, const short* __restrict__ q1,
              const short* __restrict__ q2) {
  const int i = blockIdx.x * 256 + threadIdx.x;  // 786432 threads, f32x4 each
  f32x4 a = ((const f32x4*)out)[i];
  f32x4 b = ((const f32x4*)p1)[i];
  f32x4 c = ((const f32x4*)p2)[i];
  const short4v s1 = ((const short4v*)q1)[i];
  const short4v s2 = ((const short4v*)q2)[i];
  f32x4 r;
  r.x = (a.x + b.x) + (c.x + bf2f(s1.x) + bf2f(s2.x));
  r.y = (a.y + b.y) + (c.y + bf2f(s1.y) + bf2f(s2.y));
  r.z = (a.z + b.z) + (c.z + bf2f(s1.z) + bf2f(s2.z));
  r.w = (a.w + b.w) + (c.w + bf2f(s1.w) + bf2f(s2.w));
  ((f32x4*)out)[i] = r;
}

// ---------------- launch ----------------

extern "C" void kernel_launch(void* const* d_in, const int* in_sizes, int n_in,
                              void* d_out, int out_size, void* d_ws, size_t ws_size,
                              hipStream_t stream) {
  const float* x   = (const float*)d_in[0];
  const float* nw1 = (const float*)d_in[1];
  const float* nb1 = (const float*)d_in[2];
  const float* nw2 = (const float*)d_in[3];
  const float* nb2 = (const float*)d_in[4];
  const float* lw1 = (const float*)d_in[5];
  const float* lb1 = (const float*)d_in[6];
  const float* lw2 = (const float*)d_in[7];
  const float* lb2 = (const float*)d_in[8];

  char* ws = (char*)d_ws;
  // Layout: gemm2-dead buffers first (contiguous 38.27 MB), then live ones.
  short* xb  = (short*)(ws + 0);         // 6,291,456   (dead after gemm1)
  short* BT1 = (short*)(ws + 6291456);   // 12,582,912  (dead after gemm1)
  short* BTn = (short*)(ws + 18874368);  // 1,572,864   (dead after node_cvt)
  float* hn  = (float*)(ws + 20447232);  // 16,777,216  (dead after gates)
  float* wgt = (float*)(ws + 37224448);  // 1,048,576   (dead after gemm1)
  short* BT2 = (short*)(ws + 38273024);  // 12,681,216  (live in gemm2)
  short* hs  = (short*)(ws + 50954240);  // 67,633,152  (live in gemm2)
  // split-K partials over the dead [0, 38.27 MB) region during gemm2:
  float* p1  = (float*)(ws + 0);         // 12,582,912 (f32)
  float* p2  = (float*)(ws + 12582912);  // 12,582,912 (f32)
  short* q1  = (short*)(ws + 25165824);  // 6,291,456  (bf16)
  short* q2  = (short*)(ws + 31457280);  // 6,291,456  (bf16, ends 37,748,736)

  // 1. conversions + node GEMM (fused, independent blocks)
  cvt_misc_k<<<6336, 256, 0, stream>>>(x, nw1, lb2, xb, BTn, BT2);
  node_cvt_k<<<3584, 256, 0, stream>>>(xb, BTn, hn, lw1, lw2, BT1, BT2);

  // 2. gates
  gates_k<<<1024, 256, 0, stream>>>(hn, nb1, nw2, nb2, wgt, hs);

  // 3. GEMM1 (8-phase 256^2, late-gate): hs = bf16(relu(xb@BT1^T+b1)*w)
  gemm8x<1><<<512, 512, 0, stream>>>(xb, BT1, hs, nullptr, nullptr, nullptr,
                                     nullptr, lb1, wgt);

  // 4. GEMM2 (8-phase 256^2, late-gate, split-K=5, grid 240): out = hs @ BT2^T
  gemm8x<0><<<240, 512, 0, stream>>>(hs, BT2, d_out, p1, p2, q1, q2,
                                     nullptr, nullptr);

  // 5. out += p1 + p2 + q1 + q2
  reduce_k<<<3072, 256, 0, stream>>>((float*)d_out, p1, p2, q1, q2);
}

// Round 14
// 151.211 us; speedup vs baseline: 1.0403x; 1.0403x over previous
//
#include <hip/hip_runtime.h>
#include <stdint.h>
#include <stddef.h>

typedef __attribute__((ext_vector_type(8))) short short8;
typedef __attribute__((ext_vector_type(4))) float f32x4;
typedef __attribute__((ext_vector_type(4))) short short4v;

__device__ __forceinline__ short f2bf(float f) {
  unsigned u = __builtin_bit_cast(unsigned, f);
  u = (u + 0x7fffu + ((u >> 16) & 1u)) >> 16;
  return (short)u;
}

__device__ __forceinline__ float bf2f(short s) {
  unsigned u = ((unsigned)(unsigned short)s) << 16;
  return __builtin_bit_cast(float, u);
}

__device__ __forceinline__ void gload16(const void* g, void* l) {
  __builtin_amdgcn_global_load_lds(
      (const __attribute__((address_space(1))) unsigned int*)g,
      (__attribute__((address_space(3))) unsigned int*)l, 16, 0, 0);
}

// ---------------- conversion kernels ----------------

__global__ __launch_bounds__(256)
void cvt_misc_k(const float* __restrict__ x, const float* __restrict__ nw1,
                const float* __restrict__ lb2, short* __restrict__ xb,
                short* __restrict__ BTn, short* __restrict__ BT2) {
  const int bx = blockIdx.x;
  if (bx < 3072) {
    const int i = bx * 256 + threadIdx.x;
    const float4 v = ((const float4*)x)[i];
    short4v o;
    o.x = f2bf(v.x); o.y = f2bf(v.y); o.z = f2bf(v.z); o.w = f2bf(v.w);
    *(short4v*)(xb + (size_t)i * 4) = o;
  } else if (bx < 6144) {
    const int idx = (bx - 3072) * 256 + threadIdx.x;  // 1024*768
    const int i = idx % 768;
    const int nh = idx / 768;
    float v = 0.f;
    if (nh < 1008) v = nw1[((size_t)(nh >> 4) * 768 + i) * 16 + (nh & 15)];
    BTn[idx] = f2bf(v);
  } else {
    const int idx = (bx - 6144) * 256 + threadIdx.x;  // 768*64
    const int o = idx >> 6, l = idx & 63;
    BT2[(size_t)o * 8256 + 8192 + l] = f2bf(lb2[(size_t)l * 768 + o]);
  }
}

// Fused: blocks [0,512) = node GEMM hn = xb @ BTn^T (4096x1024, K=768, BM=64);
// blocks [512, 3584) = weight transposes (lw1->BT1, lw2->BT2).
__global__ __launch_bounds__(256, 4)
void node_cvt_k(const short* __restrict__ xb, const short* __restrict__ BTn,
                float* __restrict__ hn, const float* __restrict__ lw1,
                const float* __restrict__ lw2, short* __restrict__ BT1,
                short* __restrict__ BT2) {
  __shared__ char sh[24576];
  const int tid = threadIdx.x;
  if (blockIdx.x < 512) {
    constexpr int ABYTES = 64 * 128;
    const int lane = tid & 63, wid = tid >> 6;
    const int wm = wid >> 1, wn = wid & 1;
    const int sid = (blockIdx.x & 7) * 64 + (blockIdx.x >> 3);
    const int xg = sid % 8, yg = sid / 8;
    const int m0 = yg * 64, n0 = xg * 128;
    f32x4 acc[2][4];
    const f32x4 zero = {0.f, 0.f, 0.f, 0.f};
#pragma unroll
    for (int i = 0; i < 2; ++i)
#pragma unroll
      for (int j = 0; j < 4; ++j) acc[i][j] = zero;
    for (int ki = 0; ki < 12; ++ki) {
      const int k0 = ki * 64;
      __syncthreads();
#pragma unroll
      for (int s = 0; s < 6; ++s) {
        const int off = s * 4096 + tid * 16;
        const short* src;
        if (off < ABYTES) {
          const int r = off >> 7;
          const int cs = ((off >> 4) & 7) ^ (r & 7);
          src = xb + (size_t)(m0 + r) * 768 + k0 + cs * 8;
        } else {
          const int o2 = off - ABYTES;
          const int r = o2 >> 7;
          const int cs = ((o2 >> 4) & 7) ^ (r & 7);
          src = BTn + (size_t)(n0 + r) * 768 + k0 + cs * 8;
        }
        gload16(src, sh + off);
      }
      __syncthreads();
#pragma unroll
      for (int kk = 0; kk < 2; ++kk) {
        const int chunk = kk * 4 + (lane >> 4);
        short8 af[2], bfr[4];
#pragma unroll
        for (int i = 0; i < 2; ++i) {
          const int row = wm * 32 + i * 16 + (lane & 15);
          af[i] = *(const short8*)(sh + row * 128 + ((chunk ^ (row & 7)) << 4));
        }
#pragma unroll
        for (int j = 0; j < 4; ++j) {
          const int row = wn * 64 + j * 16 + (lane & 15);
          bfr[j] = *(const short8*)(sh + ABYTES + row * 128 + ((chunk ^ (row & 7)) << 4));
        }
#pragma unroll
        for (int i = 0; i < 2; ++i)
#pragma unroll
          for (int j = 0; j < 4; ++j)
            acc[i][j] = __builtin_amdgcn_mfma_f32_16x16x32_bf16(af[i], bfr[j], acc[i][j], 0, 0, 0);
      }
    }
    const int row_base = m0 + wm * 32 + (lane >> 4) * 4;
    const int col_base = n0 + wn * 64 + (lane & 15);
#pragma unroll
    for (int i = 0; i < 2; ++i)
#pragma unroll
      for (int j = 0; j < 4; ++j)
#pragma unroll
        for (int r = 0; r < 4; ++r)
          hn[(size_t)(row_base + i * 16 + r) * 1024 + col_base + j * 16] = acc[i][j][r];
  } else {
    float (*tile)[65] = (float(*)[65])sh;
    const int cb = blockIdx.x - 512;  // [0,3072)
    const int z = cb / 24, rem = cb % 24;
    const int by = rem / 12, bxx = rem % 12;
    const int h0 = by * 64, i0 = bxx * 64;
    if (z < 64) {
      const int l = z;
#pragma unroll
      for (int t = 0; t < 16; ++t) {
        const int e = t * 256 + tid;
        const int ii = e >> 6, hh = e & 63;
        tile[ii][hh] = lw1[(size_t)l * 98304 + (size_t)(i0 + ii) * 128 + (h0 + hh)];
      }
      __syncthreads();
#pragma unroll
      for (int t = 0; t < 16; ++t) {
        const int e = t * 256 + tid;
        const int hh = e >> 6, ii = e & 63;
        BT1[(size_t)(l * 128 + h0 + hh) * 768 + i0 + ii] = f2bf(tile[ii][hh]);
      }
    } else {
      const int l = z - 64;
      const int o0 = i0;
#pragma unroll
      for (int t = 0; t < 16; ++t) {
        const int e = t * 256 + tid;
        const int hh = e >> 6, oo = e & 63;
        tile[hh][oo] = lw2[(size_t)l * 98304 + (size_t)(h0 + hh) * 768 + (o0 + oo)];
      }
      __syncthreads();
#pragma unroll
      for (int t = 0; t < 16; ++t) {
        const int e = t * 256 + tid;
        const int oo = e >> 6, hh = e & 63;
        BT2[(size_t)(o0 + oo) * 8256 + l * 128 + h0 + hh] = f2bf(tile[hh][oo]);
      }
    }
  }
}

// ---------------- gate kernel (vectorized loads) ----------------
__global__ __launch_bounds__(256)
void gates_k(const float* __restrict__ hn, const float* __restrict__ nb1,
             const float* __restrict__ nw2, const float* __restrict__ nb2,
             float* __restrict__ wgt, short* __restrict__ hs) {
  const int b = blockIdx.x * 4 + (threadIdx.x >> 6);
  const int lane = threadIdx.x & 63;
  float c = 0.f;
  if (lane < 63) {
    float s = nb2[lane];
    const float4* h4 = (const float4*)(hn + (size_t)b * 1024 + lane * 16);
    const float4* b4 = (const float4*)(nb1 + lane * 16);
    const float4* w4 = (const float4*)(nw2 + lane * 16);
#pragma unroll
    for (int j = 0; j < 4; ++j) {
      const float4 hv = h4[j], bv = b4[j], wv = w4[j];
      s += fmaxf(hv.x + bv.x, 0.f) * wv.x;
      s += fmaxf(hv.y + bv.y, 0.f) * wv.y;
      s += fmaxf(hv.z + bv.z, 0.f) * wv.z;
      s += fmaxf(hv.w + bv.w, 0.f) * wv.w;
    }
    c = 1.f / (1.f + expf(-s));
  }
  float w = 1.f;
#pragma unroll
  for (int lvl = 0; lvl < 6; ++lvl) {
    const int idx = (1 << lvl) - 1 + (lane >> (6 - lvl));
    const float g = __shfl(c, idx, 64);
    w *= ((lane >> (5 - lvl)) & 1) ? (1.f - g) : g;
  }
  wgt[(size_t)b * 64 + lane] = w;
  hs[(size_t)b * 8256 + 8192 + lane] = f2bf(w);
}

// ---------------- gemm8x: 256x256 8-phase GEMM (R12-proven early-gate) ----------------
// EPI1 (GEMM1): grid 512 = 32xg x 16yg, 2D XCD chunk (8x8 per XCD), KT=12.
// EPI0 (GEMM2): grid 240 = 3xg x 16yg x 5z (splits 26,26,26,26,25; z=4 odd tail).
//   ALL z write bf16 partials Q[z] (reduce sums 5).
template <int EPI>
__global__ __launch_bounds__(512, 2)
void gemm8x(const short* __restrict__ A, const short* __restrict__ B,
            void* __restrict__ C0, short* __restrict__ Q1, short* __restrict__ Q2,
            short* __restrict__ Q3, short* __restrict__ Q4,
            const float* __restrict__ bias, const float* __restrict__ wgt) {
  constexpr int LDA = EPI ? 768 : 8256;
  constexpr int LDB = EPI ? 768 : 8256;
  constexpr int LDC = EPI ? 8256 : 768;
  constexpr int ABYTES = 256 * 128;
  constexpr int TILEB = 2 * ABYTES;
  __shared__ char lds[2 * TILEB];

  const int tid = threadIdx.x, lane = tid & 63, wid = tid >> 6;
  const int wm = wid >> 2, wn = wid & 3;

  const int c = blockIdx.x & 7, ii = blockIdx.x >> 3;
  int xg, yg, kt0, GKT, zz;
  if constexpr (EPI == 1) {
    xg = ((c & 3) << 3) + (ii & 7);   // [0,32)
    yg = ((c >> 2) << 3) + (ii >> 3); // [0,16)
    kt0 = 0; GKT = 12; zz = 0;
  } else {
    const int uid = c * 30 + ii;  // [0,240)
    zz = uid / 48;                // [0,5)
    const int r = uid % 48;
    xg = r % 3; yg = r / 3;
    kt0 = zz * 26;
    GKT = (zz == 4) ? 25 : 26;
  }
  const int m0 = yg * 256, n0 = xg * 256;

  f32x4 acc[8][4];
  const f32x4 zero = {0.f, 0.f, 0.f, 0.f};
#pragma unroll
  for (int i = 0; i < 8; ++i)
#pragma unroll
    for (int j = 0; j < 4; ++j) acc[i][j] = zero;

  auto STG = [&](int buf, int mat, int h, int gk) {
    const int k0 = (kt0 + gk) * 64;
    char* dst = lds + buf * TILEB + mat * ABYTES + h * 16384;
    const short* base = mat ? B : A;
    const int ld = mat ? LDB : LDA;
    const int r0 = (mat ? n0 : m0) + h * 128;
#pragma unroll
    for (int s = 0; s < 2; ++s) {
      const int off = s * 8192 + tid * 16;
      const int r = off >> 7;
      const int cs = ((off >> 4) & 7) ^ (r & 7);
      gload16(base + (size_t)(r0 + r) * ld + k0 + cs * 8, dst + off);
    }
  };

  short8 bfrag[4][2];
  auto RD_B = [&](int buf) {
    const char* bB = lds + buf * TILEB + ABYTES;
#pragma unroll
    for (int j = 0; j < 4; ++j)
#pragma unroll
      for (int kk = 0; kk < 2; ++kk) {
        const int row = wn * 64 + j * 16 + (lane & 15);
        const int chunk = kk * 4 + (lane >> 4);
        bfrag[j][kk] = *(const short8*)(bB + row * 128 + ((chunk ^ (row & 7)) << 4));
      }
  };

  auto PH = [&](int buf, int q, bool rdB, int vm, auto&& stages) {
    if (rdB) RD_B(buf);
    const char* bA = lds + buf * TILEB;
    short8 af[2][2];
#pragma unroll
    for (int i = 0; i < 2; ++i)
#pragma unroll
      for (int kk = 0; kk < 2; ++kk) {
        const int row = wm * 128 + q * 32 + i * 16 + (lane & 15);
        const int chunk = kk * 4 + (lane >> 4);
        af[i][kk] = *(const short8*)(bA + row * 128 + ((chunk ^ (row & 7)) << 4));
      }
    stages();
    if (vm == 4) asm volatile("s_waitcnt vmcnt(4)" ::: "memory");
    else if (vm == 0) asm volatile("s_waitcnt vmcnt(0)" ::: "memory");
    __builtin_amdgcn_s_barrier();
    __builtin_amdgcn_s_setprio(1);
#pragma unroll
    for (int kk = 0; kk < 2; ++kk)
#pragma unroll
      for (int i = 0; i < 2; ++i)
#pragma unroll
        for (int j = 0; j < 4; ++j)
          acc[q * 2 + i][j] =
              __builtin_amdgcn_mfma_f32_16x16x32_bf16(af[i][kk], bfrag[j][kk], acc[q * 2 + i][j], 0, 0, 0);
    __builtin_amdgcn_s_setprio(0);
    __builtin_amdgcn_s_barrier();
  };

  // prologue: tile 0 (8 loads) + B(1) (4 loads); wait tile0
  STG(0, 0, 0, 0); STG(0, 0, 1, 0); STG(0, 1, 0, 0); STG(0, 1, 1, 0);
  STG(1, 1, 0, 1); STG(1, 1, 1, 1);
  asm volatile("s_waitcnt vmcnt(4)" ::: "memory");
  __builtin_amdgcn_s_barrier();

  const int iters = GKT >> 1;
  for (int it = 0; it < iters; ++it) {
    const int t0 = it * 2;
    const bool s2 = t0 + 2 < GKT, s3 = t0 + 3 < GKT;
    PH(0, 0, true, -1, [&] { STG(1, 0, 0, t0 + 1); });
    PH(0, 1, false, -1, [&] {
      STG(1, 0, 1, t0 + 1);
      if (s2) STG(0, 1, 0, t0 + 2);
    });
    PH(0, 2, false, -1, [&] { if (s2) STG(0, 1, 1, t0 + 2); });
    PH(0, 3, false, s2 ? 4 : 0, [] {});
    PH(1, 0, true, -1, [&] { if (s2) STG(0, 0, 0, t0 + 2); });
    PH(1, 1, false, -1, [&] { if (s2) STG(0, 0, 1, t0 + 2); });
    PH(1, 2, false, -1, [&] { if (s3) STG(1, 1, 0, t0 + 3); });
    PH(1, 3, false, s2 ? 4 : -1, [&] { if (s3) STG(1, 1, 1, t0 + 3); });
  }
  if (GKT & 1) {  // odd tail (EPI0 z=4): tile GKT-1 fully staged in buf0
    asm volatile("s_waitcnt vmcnt(0)" ::: "memory");
    __builtin_amdgcn_s_barrier();
    RD_B(0);
    const char* bA = lds;
#pragma unroll
    for (int q = 0; q < 4; ++q) {
      short8 af[2][2];
#pragma unroll
      for (int i = 0; i < 2; ++i)
#pragma unroll
        for (int kk = 0; kk < 2; ++kk) {
          const int row = wm * 128 + q * 32 + i * 16 + (lane & 15);
          const int chunk = kk * 4 + (lane >> 4);
          af[i][kk] = *(const short8*)(bA + row * 128 + ((chunk ^ (row & 7)) << 4));
        }
      __builtin_amdgcn_s_setprio(1);
#pragma unroll
      for (int kk = 0; kk < 2; ++kk)
#pragma unroll
        for (int i = 0; i < 2; ++i)
#pragma unroll
          for (int j = 0; j < 4; ++j)
            acc[q * 2 + i][j] =
                __builtin_amdgcn_mfma_f32_16x16x32_bf16(af[i][kk], bfrag[j][kk], acc[q * 2 + i][j], 0, 0, 0);
      __builtin_amdgcn_s_setprio(0);
    }
  }

  if constexpr (EPI == 1) {
    short* C = (short*)C0;
#pragma unroll
    for (int mi = 0; mi < 8; ++mi) {
      const int row_base = m0 + wm * 128 + mi * 16 + (lane >> 4) * 4;
#pragma unroll
      for (int j = 0; j < 4; ++j) {
        const int col = n0 + wn * 64 + j * 16 + (lane & 15);
        const int leaf = col >> 7;
        const float b = bias[col];
#pragma unroll
        for (int r = 0; r < 4; ++r) {
          const int row = row_base + r;
          const float v = fmaxf(acc[mi][j][r] + b, 0.f) * wgt[(size_t)row * 64 + leaf];
          C[(size_t)row * LDC + col] = f2bf(v);
        }
      }
    }
  } else {
    short* Q = (zz == 0) ? (short*)C0
             : (zz == 1 ? Q1 : (zz == 2 ? Q2 : (zz == 3 ? Q3 : Q4)));
#pragma unroll
    for (int mi = 0; mi < 8; ++mi) {
      const int row_base = m0 + wm * 128 + mi * 16 + (lane >> 4) * 4;
#pragma unroll
      for (int j = 0; j < 4; ++j) {
        const int col = n0 + wn * 64 + j * 16 + (lane & 15);
#pragma unroll
        for (int r = 0; r < 4; ++r)
          Q[(size_t)(row_base + r) * LDC + col] = f2bf(acc[mi][j][r]);
      }
    }
  }
}

// ---------------- split-K reduce: out = q0 + q1 + q2 + q3 + q4 (bf16 partials) ----------------
__global__ __launch_bounds__(256)
void reduce_k(float* __restrict__ out, const short* __restrict__ q0,
              const short* __restrict__ q1, const short* __restrict__ q2,
              const short* __restrict__ q3, const short* __restrict__ q4) {
  const int i = blockIdx.x * 256 + threadIdx.x;  // 786432 threads, 4 elems each
  const short4v s0 = ((const short4v*)q0)[i];
  const short4v s1 = ((const short4v*)q1)[i];
  const short4v s2 = ((const short4v*)q2)[i];
  const short4v s3 = ((const short4v*)q3)[i];
  const short4v s4 = ((const short4v*)q4)[i];
  f32x4 r;
  r.x = (bf2f(s0.x) + bf2f(s1.x)) + (bf2f(s2.x) + bf2f(s3.x)) + bf2f(s4.x);
  r.y = (bf2f(s0.y) + bf2f(s1.y)) + (bf2f(s2.y) + bf2f(s3.y)) + bf2f(s4.y);
  r.z = (bf2f(s0.z) + bf2f(s1.z)) + (bf2f(s2.z) + bf2f(s3.z)) + bf2f(s4.z);
  r.w = (bf2f(s0.w) + bf2f(s1.w)) + (bf2f(s2.w) + bf2f(s3.w)) + bf2f(s4.w);
  ((f32x4*)out)[i] = r;
}

// ---------------- launch ----------------

extern "C" void kernel_launch(void* const* d_in, const int* in_sizes, int n_in,
                              void* d_out, int out_size, void* d_ws, size_t ws_size,
                              hipStream_t stream) {
  const float* x   = (const float*)d_in[0];
  const float* nw1 = (const float*)d_in[1];
  const float* nb1 = (const float*)d_in[2];
  const float* nw2 = (const float*)d_in[3];
  const float* nb2 = (const float*)d_in[4];
  const float* lw1 = (const float*)d_in[5];
  const float* lb1 = (const float*)d_in[6];
  const float* lw2 = (const float*)d_in[7];
  const float* lb2 = (const float*)d_in[8];

  char* ws = (char*)d_ws;
  // Layout: gemm2-dead buffers first (contiguous 38.27 MB), then live ones.
  short* xb  = (short*)(ws + 0);         // 6,291,456   (dead after gemm1)
  short* BT1 = (short*)(ws + 6291456);   // 12,582,912  (dead after gemm1)
  short* BTn = (short*)(ws + 18874368);  // 1,572,864   (dead after node_cvt)
  float* hn  = (float*)(ws + 20447232);  // 16,777,216  (dead after gates)
  float* wgt = (float*)(ws + 37224448);  // 1,048,576   (dead after gemm1)
  short* BT2 = (short*)(ws + 38273024);  // 12,681,216  (live in gemm2)
  short* hs  = (short*)(ws + 50954240);  // 67,633,152  (live in gemm2)
  // bf16 split-K partials over the dead [0, 38.27 MB) region during gemm2:
  short* q0  = (short*)(ws + 0);         // 6,291,456
  short* q1  = (short*)(ws + 6291456);   // 6,291,456
  short* q2  = (short*)(ws + 12582912);  // 6,291,456
  short* q3  = (short*)(ws + 18874368);  // 6,291,456
  short* q4  = (short*)(ws + 25165824);  // 6,291,456 (ends 31,457,280)

  // 1. conversions + node GEMM (fused, independent blocks)
  cvt_misc_k<<<6336, 256, 0, stream>>>(x, nw1, lb2, xb, BTn, BT2);
  node_cvt_k<<<3584, 256, 0, stream>>>(xb, BTn, hn, lw1, lw2, BT1, BT2);

  // 2. gates
  gates_k<<<1024, 256, 0, stream>>>(hn, nb1, nw2, nb2, wgt, hs);

  // 3. GEMM1 (8-phase 256^2, R12 config): hs = bf16(relu(xb@BT1^T+b1)*w)
  gemm8x<1><<<512, 512, 0, stream>>>(xb, BT1, hs, nullptr, nullptr, nullptr,
                                     nullptr, lb1, wgt);

  // 4. GEMM2 (8-phase 256^2, split-K=5, all-bf16 partials): q[z] = partial z
  gemm8x<0><<<240, 512, 0, stream>>>(hs, BT2, q0, q1, q2, q3, q4,
                                     nullptr, nullptr);

  // 5. out = q0 + q1 + q2 + q3 + q4
  reduce_k<<<3072, 256, 0, stream>>>((float*)d_out, q0, q1, q2, q3, q4);
}

// Round 15
// 148.589 us; speedup vs baseline: 1.0587x; 1.0176x over previous
//
#include <hip/hip_runtime.h>
#include <stdint.h>
#include <stddef.h>

typedef __attribute__((ext_vector_type(8))) short short8;
typedef __attribute__((ext_vector_type(4))) float f32x4;
typedef __attribute__((ext_vector_type(4))) short short4v;

__device__ __forceinline__ short f2bf(float f) {
  unsigned u = __builtin_bit_cast(unsigned, f);
  u = (u + 0x7fffu + ((u >> 16) & 1u)) >> 16;
  return (short)u;
}

__device__ __forceinline__ float bf2f(short s) {
  unsigned u = ((unsigned)(unsigned short)s) << 16;
  return __builtin_bit_cast(float, u);
}

__device__ __forceinline__ void gload16(const void* g, void* l) {
  __builtin_amdgcn_global_load_lds(
      (const __attribute__((address_space(1))) unsigned int*)g,
      (__attribute__((address_space(3))) unsigned int*)l, 16, 0, 0);
}

// ---------------- conversion kernels ----------------

__global__ __launch_bounds__(256)
void cvt_misc_k(const float* __restrict__ x, const float* __restrict__ nw1,
                const float* __restrict__ lb2, short* __restrict__ xb,
                short* __restrict__ BTn, short* __restrict__ BT2) {
  const int bx = blockIdx.x;
  if (bx < 3072) {
    const int i = bx * 256 + threadIdx.x;
    const float4 v = ((const float4*)x)[i];
    short4v o;
    o.x = f2bf(v.x); o.y = f2bf(v.y); o.z = f2bf(v.z); o.w = f2bf(v.w);
    *(short4v*)(xb + (size_t)i * 4) = o;
  } else if (bx < 6144) {
    const int idx = (bx - 3072) * 256 + threadIdx.x;  // 1024*768
    const int i = idx % 768;
    const int nh = idx / 768;
    float v = 0.f;
    if (nh < 1008) v = nw1[((size_t)(nh >> 4) * 768 + i) * 16 + (nh & 15)];
    BTn[idx] = f2bf(v);
  } else {
    const int idx = (bx - 6144) * 256 + threadIdx.x;  // 768*64
    const int o = idx >> 6, l = idx & 63;
    BT2[(size_t)o * 8256 + 8192 + l] = f2bf(lb2[(size_t)l * 768 + o]);
  }
}

// Fused: blocks [0,512) = node GEMM + in-epilogue node-MLP finish ->
//   lg[row][node] = nb2[node] + sum_h relu(hn+nb1)*nw2   (4096 x 64 f32, 1 MB)
// blocks [512, 3584) = weight transposes (lw1->BT1, lw2->BT2).
__global__ __launch_bounds__(256, 4)
void node_cvt_k(const short* __restrict__ xb, const short* __restrict__ BTn,
                float* __restrict__ lg, const float* __restrict__ lw1,
                const float* __restrict__ lw2, short* __restrict__ BT1,
                short* __restrict__ BT2, const float* __restrict__ nb1,
                const float* __restrict__ nw2, const float* __restrict__ nb2) {
  __shared__ char sh[24576];
  const int tid = threadIdx.x;
  if (blockIdx.x < 512) {
    constexpr int ABYTES = 64 * 128;
    const int lane = tid & 63, wid = tid >> 6;
    const int wm = wid >> 1, wn = wid & 1;
    const int sid = (blockIdx.x & 7) * 64 + (blockIdx.x >> 3);
    const int xg = sid % 8, yg = sid / 8;
    const int m0 = yg * 64, n0 = xg * 128;
    f32x4 acc[2][4];
    const f32x4 zero = {0.f, 0.f, 0.f, 0.f};
#pragma unroll
    for (int i = 0; i < 2; ++i)
#pragma unroll
      for (int j = 0; j < 4; ++j) acc[i][j] = zero;
    for (int ki = 0; ki < 12; ++ki) {
      const int k0 = ki * 64;
      __syncthreads();
#pragma unroll
      for (int s = 0; s < 6; ++s) {
        const int off = s * 4096 + tid * 16;
        const short* src;
        if (off < ABYTES) {
          const int r = off >> 7;
          const int cs = ((off >> 4) & 7) ^ (r & 7);
          src = xb + (size_t)(m0 + r) * 768 + k0 + cs * 8;
        } else {
          const int o2 = off - ABYTES;
          const int r = o2 >> 7;
          const int cs = ((o2 >> 4) & 7) ^ (r & 7);
          src = BTn + (size_t)(n0 + r) * 768 + k0 + cs * 8;
        }
        gload16(src, sh + off);
      }
      __syncthreads();
#pragma unroll
      for (int kk = 0; kk < 2; ++kk) {
        const int chunk = kk * 4 + (lane >> 4);
        short8 af[2], bfr[4];
#pragma unroll
        for (int i = 0; i < 2; ++i) {
          const int row = wm * 32 + i * 16 + (lane & 15);
          af[i] = *(const short8*)(sh + row * 128 + ((chunk ^ (row & 7)) << 4));
        }
#pragma unroll
        for (int j = 0; j < 4; ++j) {
          const int row = wn * 64 + j * 16 + (lane & 15);
          bfr[j] = *(const short8*)(sh + ABYTES + row * 128 + ((chunk ^ (row & 7)) << 4));
        }
#pragma unroll
        for (int i = 0; i < 2; ++i)
#pragma unroll
          for (int j = 0; j < 4; ++j)
            acc[i][j] = __builtin_amdgcn_mfma_f32_16x16x32_bf16(af[i], bfr[j], acc[i][j], 0, 0, 0);
      }
    }
    // Epilogue: finish the node MLP in-register.
    // For fixed j, the 16 lanes (lane&15) hold node (xg*8+wn*4+j)'s 16 hidden
    // units for row = m0 + wm*32 + i*16 + (lane>>4)*4 + r.
    const int row_base = m0 + wm * 32 + (lane >> 4) * 4;
    const int node_base = (n0 >> 4) + wn * 4;
#pragma unroll
    for (int j = 0; j < 4; ++j) {
      const int node = node_base + j;
      float b1v = 0.f, w2v = 0.f, b2v = 0.f;
      if (node < 63) {  // node 63 is the zero-pad slot; nb1/nw2 have 1008 elems
        b1v = nb1[node * 16 + (lane & 15)];
        w2v = nw2[node * 16 + (lane & 15)];
        b2v = nb2[node];
      }
#pragma unroll
      for (int i = 0; i < 2; ++i)
#pragma unroll
        for (int r = 0; r < 4; ++r) {
          float v = fmaxf(acc[i][j][r] + b1v, 0.f) * w2v;
#pragma unroll
          for (int o = 8; o; o >>= 1) v += __shfl_xor(v, o, 16);
          if ((lane & 15) == 0)
            lg[(size_t)(row_base + i * 16 + r) * 64 + node] = v + b2v;
        }
    }
  } else {
    float (*tile)[65] = (float(*)[65])sh;
    const int cb = blockIdx.x - 512;  // [0,3072)
    const int z = cb / 24, rem = cb % 24;
    const int by = rem / 12, bxx = rem % 12;
    const int h0 = by * 64, i0 = bxx * 64;
    if (z < 64) {
      const int l = z;
#pragma unroll
      for (int t = 0; t < 16; ++t) {
        const int e = t * 256 + tid;
        const int ii = e >> 6, hh = e & 63;
        tile[ii][hh] = lw1[(size_t)l * 98304 + (size_t)(i0 + ii) * 128 + (h0 + hh)];
      }
      __syncthreads();
#pragma unroll
      for (int t = 0; t < 16; ++t) {
        const int e = t * 256 + tid;
        const int hh = e >> 6, ii = e & 63;
        BT1[(size_t)(l * 128 + h0 + hh) * 768 + i0 + ii] = f2bf(tile[ii][hh]);
      }
    } else {
      const int l = z - 64;
      const int o0 = i0;
#pragma unroll
      for (int t = 0; t < 16; ++t) {
        const int e = t * 256 + tid;
        const int hh = e >> 6, oo = e & 63;
        tile[hh][oo] = lw2[(size_t)l * 98304 + (size_t)(h0 + hh) * 768 + (o0 + oo)];
      }
      __syncthreads();
#pragma unroll
      for (int t = 0; t < 16; ++t) {
        const int e = t * 256 + tid;
        const int oo = e >> 6, hh = e & 63;
        BT2[(size_t)(o0 + oo) * 8256 + l * 128 + h0 + hh] = f2bf(tile[hh][oo]);
      }
    }
  }
}

// ---------------- gate kernel: sigmoid + tree product from logits ----------------
__global__ __launch_bounds__(256)
void gates_k(const float* __restrict__ lg, float* __restrict__ wgt,
             short* __restrict__ hs) {
  const int b = blockIdx.x * 4 + (threadIdx.x >> 6);
  const int lane = threadIdx.x & 63;
  float c = 0.f;
  if (lane < 63) {
    const float s = lg[(size_t)b * 64 + lane];
    c = 1.f / (1.f + expf(-s));
  }
  float w = 1.f;
#pragma unroll
  for (int lvl = 0; lvl < 6; ++lvl) {
    const int idx = (1 << lvl) - 1 + (lane >> (6 - lvl));
    const float g = __shfl(c, idx, 64);
    w *= ((lane >> (5 - lvl)) & 1) ? (1.f - g) : g;
  }
  wgt[(size_t)b * 64 + lane] = w;
  hs[(size_t)b * 8256 + 8192 + lane] = f2bf(w);
}

// ---------------- gemm8x: 256x256 8-phase GEMM (R12-proven early-gate) ----------------
// EPI1 (GEMM1): grid 512 = 32xg x 16yg, 2D XCD chunk (8x8 per XCD), KT=12.
// EPI0 (GEMM2): grid 240 = 3xg x 16yg x 5z (splits 26,26,26,26,25; z=4 odd tail).
//   ALL z write bf16 partials Q[z] (reduce sums 5).
template <int EPI>
__global__ __launch_bounds__(512, 2)
void gemm8x(const short* __restrict__ A, const short* __restrict__ B,
            void* __restrict__ C0, short* __restrict__ Q1, short* __restrict__ Q2,
            short* __restrict__ Q3, short* __restrict__ Q4,
            const float* __restrict__ bias, const float* __restrict__ wgt) {
  constexpr int LDA = EPI ? 768 : 8256;
  constexpr int LDB = EPI ? 768 : 8256;
  constexpr int LDC = EPI ? 8256 : 768;
  constexpr int ABYTES = 256 * 128;
  constexpr int TILEB = 2 * ABYTES;
  __shared__ char lds[2 * TILEB];

  const int tid = threadIdx.x, lane = tid & 63, wid = tid >> 6;
  const int wm = wid >> 2, wn = wid & 3;

  const int c = blockIdx.x & 7, ii = blockIdx.x >> 3;
  int xg, yg, kt0, GKT, zz;
  if constexpr (EPI == 1) {
    xg = ((c & 3) << 3) + (ii & 7);   // [0,32)
    yg = ((c >> 2) << 3) + (ii >> 3); // [0,16)
    kt0 = 0; GKT = 12; zz = 0;
  } else {
    const int uid = c * 30 + ii;  // [0,240)
    zz = uid / 48;                // [0,5)
    const int r = uid % 48;
    xg = r % 3; yg = r / 3;
    kt0 = zz * 26;
    GKT = (zz == 4) ? 25 : 26;
  }
  const int m0 = yg * 256, n0 = xg * 256;

  f32x4 acc[8][4];
  const f32x4 zero = {0.f, 0.f, 0.f, 0.f};
#pragma unroll
  for (int i = 0; i < 8; ++i)
#pragma unroll
    for (int j = 0; j < 4; ++j) acc[i][j] = zero;

  auto STG = [&](int buf, int mat, int h, int gk) {
    const int k0 = (kt0 + gk) * 64;
    char* dst = lds + buf * TILEB + mat * ABYTES + h * 16384;
    const short* base = mat ? B : A;
    const int ld = mat ? LDB : LDA;
    const int r0 = (mat ? n0 : m0) + h * 128;
#pragma unroll
    for (int s = 0; s < 2; ++s) {
      const int off = s * 8192 + tid * 16;
      const int r = off >> 7;
      const int cs = ((off >> 4) & 7) ^ (r & 7);
      gload16(base + (size_t)(r0 + r) * ld + k0 + cs * 8, dst + off);
    }
  };

  short8 bfrag[4][2];
  auto RD_B = [&](int buf) {
    const char* bB = lds + buf * TILEB + ABYTES;
#pragma unroll
    for (int j = 0; j < 4; ++j)
#pragma unroll
      for (int kk = 0; kk < 2; ++kk) {
        const int row = wn * 64 + j * 16 + (lane & 15);
        const int chunk = kk * 4 + (lane >> 4);
        bfrag[j][kk] = *(const short8*)(bB + row * 128 + ((chunk ^ (row & 7)) << 4));
      }
  };

  auto PH = [&](int buf, int q, bool rdB, int vm, auto&& stages) {
    if (rdB) RD_B(buf);
    const char* bA = lds + buf * TILEB;
    short8 af[2][2];
#pragma unroll
    for (int i = 0; i < 2; ++i)
#pragma unroll
      for (int kk = 0; kk < 2; ++kk) {
        const int row = wm * 128 + q * 32 + i * 16 + (lane & 15);
        const int chunk = kk * 4 + (lane >> 4);
        af[i][kk] = *(const short8*)(bA + row * 128 + ((chunk ^ (row & 7)) << 4));
      }
    stages();
    if (vm == 4) asm volatile("s_waitcnt vmcnt(4)" ::: "memory");
    else if (vm == 0) asm volatile("s_waitcnt vmcnt(0)" ::: "memory");
    __builtin_amdgcn_s_barrier();
    __builtin_amdgcn_s_setprio(1);
#pragma unroll
    for (int kk = 0; kk < 2; ++kk)
#pragma unroll
      for (int i = 0; i < 2; ++i)
#pragma unroll
        for (int j = 0; j < 4; ++j)
          acc[q * 2 + i][j] =
              __builtin_amdgcn_mfma_f32_16x16x32_bf16(af[i][kk], bfrag[j][kk], acc[q * 2 + i][j], 0, 0, 0);
    __builtin_amdgcn_s_setprio(0);
    __builtin_amdgcn_s_barrier();
  };

  // prologue: tile 0 (8 loads) + B(1) (4 loads); wait tile0
  STG(0, 0, 0, 0); STG(0, 0, 1, 0); STG(0, 1, 0, 0); STG(0, 1, 1, 0);
  STG(1, 1, 0, 1); STG(1, 1, 1, 1);
  asm volatile("s_waitcnt vmcnt(4)" ::: "memory");
  __builtin_amdgcn_s_barrier();

  const int iters = GKT >> 1;
  for (int it = 0; it < iters; ++it) {
    const int t0 = it * 2;
    const bool s2 = t0 + 2 < GKT, s3 = t0 + 3 < GKT;
    PH(0, 0, true, -1, [&] { STG(1, 0, 0, t0 + 1); });
    PH(0, 1, false, -1, [&] {
      STG(1, 0, 1, t0 + 1);
      if (s2) STG(0, 1, 0, t0 + 2);
    });
    PH(0, 2, false, -1, [&] { if (s2) STG(0, 1, 1, t0 + 2); });
    PH(0, 3, false, s2 ? 4 : 0, [] {});
    PH(1, 0, true, -1, [&] { if (s2) STG(0, 0, 0, t0 + 2); });
    PH(1, 1, false, -1, [&] { if (s2) STG(0, 0, 1, t0 + 2); });
    PH(1, 2, false, -1, [&] { if (s3) STG(1, 1, 0, t0 + 3); });
    PH(1, 3, false, s2 ? 4 : -1, [&] { if (s3) STG(1, 1, 1, t0 + 3); });
  }
  if (GKT & 1) {  // odd tail (EPI0 z=4): tile GKT-1 fully staged in buf0
    asm volatile("s_waitcnt vmcnt(0)" ::: "memory");
    __builtin_amdgcn_s_barrier();
    RD_B(0);
    const char* bA = lds;
#pragma unroll
    for (int q = 0; q < 4; ++q) {
      short8 af[2][2];
#pragma unroll
      for (int i = 0; i < 2; ++i)
#pragma unroll
        for (int kk = 0; kk < 2; ++kk) {
          const int row = wm * 128 + q * 32 + i * 16 + (lane & 15);
          const int chunk = kk * 4 + (lane >> 4);
          af[i][kk] = *(const short8*)(bA + row * 128 + ((chunk ^ (row & 7)) << 4));
        }
      __builtin_amdgcn_s_setprio(1);
#pragma unroll
      for (int kk = 0; kk < 2; ++kk)
#pragma unroll
        for (int i = 0; i < 2; ++i)
#pragma unroll
          for (int j = 0; j < 4; ++j)
            acc[q * 2 + i][j] =
                __builtin_amdgcn_mfma_f32_16x16x32_bf16(af[i][kk], bfrag[j][kk], acc[q * 2 + i][j], 0, 0, 0);
      __builtin_amdgcn_s_setprio(0);
    }
  }

  if constexpr (EPI == 1) {
    short* C = (short*)C0;
#pragma unroll
    for (int mi = 0; mi < 8; ++mi) {
      const int row_base = m0 + wm * 128 + mi * 16 + (lane >> 4) * 4;
#pragma unroll
      for (int j = 0; j < 4; ++j) {
        const int col = n0 + wn * 64 + j * 16 + (lane & 15);
        const int leaf = col >> 7;
        const float b = bias[col];
#pragma unroll
        for (int r = 0; r < 4; ++r) {
          const int row = row_base + r;
          const float v = fmaxf(acc[mi][j][r] + b, 0.f) * wgt[(size_t)row * 64 + leaf];
          C[(size_t)row * LDC + col] = f2bf(v);
        }
      }
    }
  } else {
    short* Q = (zz == 0) ? (short*)C0
             : (zz == 1 ? Q1 : (zz == 2 ? Q2 : (zz == 3 ? Q3 : Q4)));
#pragma unroll
    for (int mi = 0; mi < 8; ++mi) {
      const int row_base = m0 + wm * 128 + mi * 16 + (lane >> 4) * 4;
#pragma unroll
      for (int j = 0; j < 4; ++j) {
        const int col = n0 + wn * 64 + j * 16 + (lane & 15);
#pragma unroll
        for (int r = 0; r < 4; ++r)
          Q[(size_t)(row_base + r) * LDC + col] = f2bf(acc[mi][j][r]);
      }
    }
  }
}

// ---------------- split-K reduce: out = q0 + q1 + q2 + q3 + q4 (bf16 partials) ----------------
__global__ __launch_bounds__(256)
void reduce_k(float* __restrict__ out, const short* __restrict__ q0,
              const short* __restrict__ q1, const short* __restrict__ q2,
              const short* __restrict__ q3, const short* __restrict__ q4) {
  const int i = blockIdx.x * 256 + threadIdx.x;  // 786432 threads, 4 elems each
  const short4v s0 = ((const short4v*)q0)[i];
  const short4v s1 = ((const short4v*)q1)[i];
  const short4v s2 = ((const short4v*)q2)[i];
  const short4v s3 = ((const short4v*)q3)[i];
  const short4v s4 = ((const short4v*)q4)[i];
  f32x4 r;
  r.x = (bf2f(s0.x) + bf2f(s1.x)) + (bf2f(s2.x) + bf2f(s3.x)) + bf2f(s4.x);
  r.y = (bf2f(s0.y) + bf2f(s1.y)) + (bf2f(s2.y) + bf2f(s3.y)) + bf2f(s4.y);
  r.z = (bf2f(s0.z) + bf2f(s1.z)) + (bf2f(s2.z) + bf2f(s3.z)) + bf2f(s4.z);
  r.w = (bf2f(s0.w) + bf2f(s1.w)) + (bf2f(s2.w) + bf2f(s3.w)) + bf2f(s4.w);
  ((f32x4*)out)[i] = r;
}

// ---------------- launch ----------------

extern "C" void kernel_launch(void* const* d_in, const int* in_sizes, int n_in,
                              void* d_out, int out_size, void* d_ws, size_t ws_size,
                              hipStream_t stream) {
  const float* x   = (const float*)d_in[0];
  const float* nw1 = (const float*)d_in[1];
  const float* nb1 = (const float*)d_in[2];
  const float* nw2 = (const float*)d_in[3];
  const float* nb2 = (const float*)d_in[4];
  const float* lw1 = (const float*)d_in[5];
  const float* lb1 = (const float*)d_in[6];
  const float* lw2 = (const float*)d_in[7];
  const float* lb2 = (const float*)d_in[8];

  char* ws = (char*)d_ws;
  // Layout: gemm2-dead buffers first (contiguous 38.27 MB), then live ones.
  short* xb  = (short*)(ws + 0);         // 6,291,456   (dead after gemm1)
  short* BT1 = (short*)(ws + 6291456);   // 12,582,912  (dead after gemm1)
  short* BTn = (short*)(ws + 18874368);  // 1,572,864   (dead after node_cvt)
  float* lg  = (float*)(ws + 20447232);  // 1,048,576   (4096x64 logits; dead after gates)
  float* wgt = (float*)(ws + 37224448);  // 1,048,576   (dead after gemm1)
  short* BT2 = (short*)(ws + 38273024);  // 12,681,216  (live in gemm2)
  short* hs  = (short*)(ws + 50954240);  // 67,633,152  (live in gemm2)
  // bf16 split-K partials over the dead [0, 38.27 MB) region during gemm2:
  short* q0  = (short*)(ws + 0);         // 6,291,456
  short* q1  = (short*)(ws + 6291456);   // 6,291,456
  short* q2  = (short*)(ws + 12582912);  // 6,291,456
  short* q3  = (short*)(ws + 18874368);  // 6,291,456
  short* q4  = (short*)(ws + 25165824);  // 6,291,456 (ends 31,457,280)

  // 1. conversions + node GEMM w/ fused node-MLP epilogue
  cvt_misc_k<<<6336, 256, 0, stream>>>(x, nw1, lb2, xb, BTn, BT2);
  node_cvt_k<<<3584, 256, 0, stream>>>(xb, BTn, lg, lw1, lw2, BT1, BT2,
                                       nb1, nw2, nb2);

  // 2. gates: sigmoid(logits) -> tree-path weights
  gates_k<<<1024, 256, 0, stream>>>(lg, wgt, hs);

  // 3. GEMM1 (8-phase 256^2, R12 config): hs = bf16(relu(xb@BT1^T+b1)*w)
  gemm8x<1><<<512, 512, 0, stream>>>(xb, BT1, hs, nullptr, nullptr, nullptr,
                                     nullptr, lb1, wgt);

  // 4. GEMM2 (8-phase 256^2, split-K=5, all-bf16 partials): q[z] = partial z
  gemm8x<0><<<240, 512, 0, stream>>>(hs, BT2, q0, q1, q2, q3, q4,
                                     nullptr, nullptr);

  // 5. out = q0 + q1 + q2 + q3 + q4
  reduce_k<<<3072, 256, 0, stream>>>((float*)d_out, q0, q1, q2, q3, q4);
}